// Round 2
// baseline (10379.229 us; speedup 1.0000x reference)
//
#include <hip/hip_runtime.h>
#include <hip/hip_bf16.h>

typedef __attribute__((ext_vector_type(8))) short bf16x8;
typedef __attribute__((ext_vector_type(4))) float f32x4;

// Problem sizes (fixed)
//   B=64, L=1024, I=256, H=512
// d_in order: 0 inputs, 1 hidden_states, 2 w_ir, 3 w_iz, 4 w_in, 5 b_ir, 6 b_iz,
//             7 b_in, 8 w_hr, 9 w_hz, 10 w_hn, 11 b_hr, 12 b_hz, 13 b_hn

__device__ __forceinline__ unsigned short f2bf(float f) {
    __hip_bfloat16 h = __float2bfloat16(f);   // RNE
    return __builtin_bit_cast(unsigned short, h);
}
__device__ __forceinline__ float bf2f(unsigned short u) {
    union { unsigned int i; float f; } c; c.i = ((unsigned int)u) << 16; return c.f;
}

// ---------------------------------------------------------------- pack inputs
// fp32 [64][1024][256] -> bf16 (rows m = b*1024+t are contiguous I=256)
__global__ void pack_inputs(const float* __restrict__ in, unsigned short* __restrict__ out) {
    int i = blockIdx.x * 256 + threadIdx.x;          // 16384 blocks: i < 4194304
    float4 v = reinterpret_cast<const float4*>(in)[i];
    ushort4 u;
    u.x = f2bf(v.x); u.y = f2bf(v.y); u.z = f2bf(v.z); u.w = f2bf(v.w);
    reinterpret_cast<ushort4*>(out)[i] = u;
}

// ---------------------------------------------------------------- pack weights
// Wx  bf16 [1536][256]  (n = g*512 + j; g: 0=r,1=z,2=n)
// Wh  bf16 [3][512][512]
// biasx fp32 [1536]: r: b_ir+b_hr, z: b_iz+b_hz, n: b_in (b_hn applied inside r*(...))
// Also zero-inits the grid barrier counter (ws is re-poisoned before each call).
__global__ void pack_weights(const float* __restrict__ w_ir, const float* __restrict__ w_iz,
                             const float* __restrict__ w_in, const float* __restrict__ b_ir,
                             const float* __restrict__ b_iz, const float* __restrict__ b_in,
                             const float* __restrict__ w_hr, const float* __restrict__ w_hz,
                             const float* __restrict__ w_hn, const float* __restrict__ b_hr,
                             const float* __restrict__ b_hz,
                             unsigned short* __restrict__ Wx, unsigned short* __restrict__ Wh,
                             float* __restrict__ biasx, unsigned int* __restrict__ bar) {
    int i = blockIdx.x * 256 + threadIdx.x;          // 3072 blocks: i < 786432
    {
        int g = i / 262144, rem = i % 262144;
        const float* src = (g == 0) ? w_hr : ((g == 1) ? w_hz : w_hn);
        Wh[i] = f2bf(src[rem]);
    }
    if (i < 393216) {
        int g = i / 131072, rem = i % 131072;
        const float* src = (g == 0) ? w_ir : ((g == 1) ? w_iz : w_in);
        Wx[i] = f2bf(src[rem]);
    }
    if (i < 1536) {
        int g = i / 512, j = i % 512;
        float v = (g == 0) ? (b_ir[j] + b_hr[j]) : ((g == 1) ? (b_iz[j] + b_hz[j]) : b_in[j]);
        biasx[i] = v;
    }
    if (i == 0) *bar = 0u;
}

// ---------------------------------------------------------------- input projection GEMM
// C[m][n] = sum_k A[m][k]*Wx[n][k] + biasx[n],  M=65536, N=1536, K=256
// written as bf16 X[t][b][n] with t = m & 1023, b = m >> 10.
__global__ __launch_bounds__(256) void xproj_gemm(
    const unsigned short* __restrict__ A,    // [65536][256] bf16
    const unsigned short* __restrict__ Bw,   // [1536][256]  bf16
    const float* __restrict__ biasx,         // [1536]
    unsigned short* __restrict__ X)          // [1024][64][1536] bf16
{
    __shared__ __attribute__((aligned(16))) unsigned short Al[64][40]; // +8 pad: 2-way banks (free)
    __shared__ __attribute__((aligned(16))) unsigned short Bl[64][40];
    const int tid  = threadIdx.x;
    const int m0   = blockIdx.x * 64;
    const int n0   = blockIdx.y * 64;
    const int lane = tid & 63;
    const int wv   = tid >> 6;
    const int quad = lane >> 4;
    const int l16  = lane & 15;
    const int mw   = (wv & 1) * 32;
    const int nw   = (wv >> 1) * 32;
    const int lr   = tid >> 2;          // 0..63 staging row
    const int lc   = (tid & 3) * 8;     // k offset within BK=32

    f32x4 acc[2][2] = {};

    for (int kb = 0; kb < 8; ++kb) {
        uint4 av = *reinterpret_cast<const uint4*>(A  + (size_t)(m0 + lr) * 256 + kb * 32 + lc);
        uint4 bv = *reinterpret_cast<const uint4*>(Bw + (size_t)(n0 + lr) * 256 + kb * 32 + lc);
        __syncthreads();
        *reinterpret_cast<uint4*>(&Al[lr][lc]) = av;
        *reinterpret_cast<uint4*>(&Bl[lr][lc]) = bv;
        __syncthreads();
        bf16x8 af[2], bfg[2];
#pragma unroll
        for (int s = 0; s < 2; ++s) {
            af[s]  = *reinterpret_cast<const bf16x8*>(&Al[mw + s * 16 + l16][quad * 8]);
            bfg[s] = *reinterpret_cast<const bf16x8*>(&Bl[nw + s * 16 + l16][quad * 8]);
        }
#pragma unroll
        for (int sm = 0; sm < 2; ++sm)
#pragma unroll
            for (int sn = 0; sn < 2; ++sn)
                acc[sm][sn] = __builtin_amdgcn_mfma_f32_16x16x32_bf16(af[sm], bfg[sn], acc[sm][sn], 0, 0, 0);
    }
    // epilogue: D layout col = lane&15 (n), row = quad*4 + r (m)
#pragma unroll
    for (int sn = 0; sn < 2; ++sn) {
        int n = n0 + nw + sn * 16 + l16;
        float bias = biasx[n];
#pragma unroll
        for (int sm = 0; sm < 2; ++sm)
#pragma unroll
            for (int r = 0; r < 4; ++r) {
                int m = m0 + mw + sm * 16 + quad * 4 + r;
                int t = m & 1023, b = m >> 10;
                X[(size_t)(t * 64 + b) * 1536 + n] = f2bf(acc[sm][sn][r] + bias);
            }
    }
}

// ---------------------------------------------------------------- grid barrier
// Monotone-counter barrier across NB blocks, no cooperative launch needed.
// 32 blocks << 256 CUs at 1 block/CU => all blocks resident, spin is safe.
// atomicAdd on global is device-scope by default [m20]; __threadfence() is an
// agent-scope fence (release: L2 writeback / acquire: L1+L2 invalidate) which
// is required for cross-XCD visibility of the Hbuf exchange.
template <unsigned int NB>
__device__ __forceinline__ void grid_barrier(unsigned int* bar) {
    __threadfence();           // all threads: release own Hbuf stores device-wide
    __syncthreads();
    if (threadIdx.x == 0) {
        unsigned int arrive = atomicAdd(bar, 1u);
        unsigned int target = (arrive / NB + 1u) * NB;
        while (__hip_atomic_load(bar, __ATOMIC_RELAXED, __HIP_MEMORY_SCOPE_AGENT) < target) { }
        __threadfence();       // acquire: invalidate caches before reading peers' h
    }
    __syncthreads();
    __threadfence();           // belt+suspenders: every wave invalidates before reads
}

// ---------------------------------------------------------------- recurrent scan
// 32 workgroups x 256 threads, plain launch. Workgroup `bid` owns output dims
// j in [bid*16, bid*16+16) for each of the 3 gates; its weight B-fragments
// (3 gates x 16 k-iters = 192 VGPRs/lane) stay register-resident for all
// 1024 steps. h exchanged through double-buffered global bf16 Hbuf with the
// manual grid barrier above.
__global__ __launch_bounds__(256, 1) void gru_scan(
    const unsigned short* __restrict__ X,    // [1024][64][1536] bf16 (biases folded)
    const unsigned short* __restrict__ Wh,   // [3][512][512] bf16
    const float* __restrict__ h0,            // [1][64][512]
    const float* __restrict__ b_hn,          // [512]
    unsigned short* __restrict__ Hbuf,       // [2][64][512] bf16
    unsigned int* __restrict__ bar,          // barrier counter (zeroed by pack_weights)
    float* __restrict__ out)                 // [64][1024][512] fp32, then hlast [64][512]
{
    const int tid  = threadIdx.x;
    const int lane = tid & 63;
    const int w    = tid >> 6;      // wave 0..3 -> batch rows 16w..16w+15
    const int quad = lane >> 4;
    const int jl   = lane & 15;
    const int bid  = blockIdx.x;    // 0..31
    const int jg   = bid * 16 + jl; // this lane's output dim (per gate)

    // Hoist weight B-fragments: B[k][n] layout, lane n = lane&15 holds row j=jg,
    // k = kk*32 + quad*8 + (0..7) -> contiguous 16B from Wh[g][jg][...]
    bf16x8 bfrag[3][16];
#pragma unroll
    for (int g = 0; g < 3; ++g)
#pragma unroll
        for (int kk = 0; kk < 16; ++kk) {
            uint4 v = *reinterpret_cast<const uint4*>(
                Wh + (size_t)(g * 512 + jg) * 512 + kk * 32 + quad * 8);
            bfrag[g][kk] = __builtin_bit_cast(bf16x8, v);
        }
    const float bhn = b_hn[jg];

    // init h (C/D row mapping: b = 16w + quad*4 + r, col = jg)
    float h_reg[4];
#pragma unroll
    for (int r = 0; r < 4; ++r) {
        int b = w * 16 + quad * 4 + r;
        float h = h0[b * 512 + jg];
        h_reg[r] = h;
        Hbuf[b * 512 + jg] = f2bf(h);
    }

    grid_barrier<32>(bar);

    const int arow = w * 16 + jl;   // A-fragment row this lane loads (m = lane&15)

    // preload x projections for t=0
    float xv[3][4];
#pragma unroll
    for (int r = 0; r < 4; ++r) {
        int b = w * 16 + quad * 4 + r;
#pragma unroll
        for (int g = 0; g < 3; ++g)
            xv[g][r] = bf2f(X[(size_t)b * 1536 + g * 512 + jg]);
    }

    for (int t = 0; t < 1024; ++t) {
        const int cur = t & 1;
        const int nxt = cur ^ 1;

        // A fragments: h rows (A[m=lane&15][k=quad*8+j])
        bf16x8 afrag[16];
#pragma unroll
        for (int kk = 0; kk < 16; ++kk) {
            uint4 v = *reinterpret_cast<const uint4*>(
                Hbuf + (size_t)(cur * 64 + arow) * 512 + kk * 32 + quad * 8);
            afrag[kk] = __builtin_bit_cast(bf16x8, v);
        }

        f32x4 acc[3];
#pragma unroll
        for (int g = 0; g < 3; ++g) {
            f32x4 a = {0.f, 0.f, 0.f, 0.f};
#pragma unroll
            for (int kk = 0; kk < 16; ++kk)
                a = __builtin_amdgcn_mfma_f32_16x16x32_bf16(afrag[kk], bfrag[g][kk], a, 0, 0, 0);
            acc[g] = a;
        }

#pragma unroll
        for (int r = 0; r < 4; ++r) {
            int b = w * 16 + quad * 4 + r;
            float rv = 1.f / (1.f + __expf(-(xv[0][r] + acc[0][r])));
            float zv = 1.f / (1.f + __expf(-(xv[1][r] + acc[1][r])));
            float na = xv[2][r] + rv * (acc[2][r] + bhn);
            float nv = 1.f - 2.f / (1.f + __expf(2.f * na));   // tanh, inf-safe
            float h  = (1.f - zv) * nv + zv * h_reg[r];
            h_reg[r] = h;
            out[(size_t)b * (1024 * 512) + (size_t)t * 512 + jg] = h;
            Hbuf[(size_t)(nxt * 64 + b) * 512 + jg] = f2bf(h);
        }
        if (t == 1023) {
#pragma unroll
            for (int r = 0; r < 4; ++r) {
                int b = w * 16 + quad * 4 + r;
                out[(size_t)(64 * 1024 * 512) + b * 512 + jg] = h_reg[r];
            }
        } else {
            // prefetch next step's x projections; loads retire during the barrier spin
            const unsigned short* Xt = X + (size_t)(t + 1) * (64 * 1536);
#pragma unroll
            for (int r = 0; r < 4; ++r) {
                int b = w * 16 + quad * 4 + r;
#pragma unroll
                for (int g = 0; g < 3; ++g)
                    xv[g][r] = bf2f(Xt[b * 1536 + g * 512 + jg]);
            }
        }

        grid_barrier<32>(bar);
    }
}

// ---------------------------------------------------------------- host
extern "C" void kernel_launch(void* const* d_in, const int* in_sizes, int n_in,
                              void* d_out, int out_size, void* d_ws, size_t ws_size,
                              hipStream_t stream) {
    const float* inputs = (const float*)d_in[0];
    const float* h0     = (const float*)d_in[1];
    const float* w_ir   = (const float*)d_in[2];
    const float* w_iz   = (const float*)d_in[3];
    const float* w_in   = (const float*)d_in[4];
    const float* b_ir   = (const float*)d_in[5];
    const float* b_iz   = (const float*)d_in[6];
    const float* b_in   = (const float*)d_in[7];
    const float* w_hr   = (const float*)d_in[8];
    const float* w_hz   = (const float*)d_in[9];
    const float* w_hn   = (const float*)d_in[10];
    const float* b_hr   = (const float*)d_in[11];
    const float* b_hz   = (const float*)d_in[12];
    const float* b_hn   = (const float*)d_in[13];
    float* out = (float*)d_out;

    // ws layout (all 16B aligned), total 237,377,544 bytes
    char* wsb = (char*)d_ws;
    unsigned short* X     = (unsigned short*)(wsb);              // 201326592 B
    unsigned short* Abf   = (unsigned short*)(wsb + 201326592);  //  33554432 B
    unsigned short* Wx    = (unsigned short*)(wsb + 234881024);  //    786432 B
    unsigned short* Wh    = (unsigned short*)(wsb + 235667456);  //   1572864 B
    float*          biasx = (float*)        (wsb + 237240320);   //      6144 B
    unsigned short* Hbuf  = (unsigned short*)(wsb + 237246464);  //    131072 B
    unsigned int*   bar   = (unsigned int*) (wsb + 237377536);   //         4 B

    pack_inputs<<<16384, 256, 0, stream>>>(inputs, Abf);
    pack_weights<<<3072, 256, 0, stream>>>(w_ir, w_iz, w_in, b_ir, b_iz, b_in,
                                           w_hr, w_hz, w_hn, b_hr, b_hz, Wx, Wh, biasx, bar);
    xproj_gemm<<<dim3(1024, 24), 256, 0, stream>>>(Abf, Wx, biasx, X);
    gru_scan<<<32, 256, 0, stream>>>(X, Wh, h0, b_hn, Hbuf, bar, out);
}

// Round 3
// 6313.176 us; speedup vs baseline: 1.6441x; 1.6441x over previous
//
#include <hip/hip_runtime.h>
#include <hip/hip_bf16.h>

typedef __attribute__((ext_vector_type(8))) short bf16x8;
typedef __attribute__((ext_vector_type(4))) float f32x4;

// Problem sizes (fixed): B=64, L=1024, I=256, H=512
// d_in order: 0 inputs, 1 hidden_states, 2 w_ir, 3 w_iz, 4 w_in, 5 b_ir, 6 b_iz,
//             7 b_in, 8 w_hr, 9 w_hz, 10 w_hn, 11 b_hr, 12 b_hz, 13 b_hn

__device__ __forceinline__ unsigned short f2bf(float f) {
    __hip_bfloat16 h = __float2bfloat16(f);   // RNE
    return __builtin_bit_cast(unsigned short, h);
}
__device__ __forceinline__ float bf2f(unsigned short u) {
    union { unsigned int i; float f; } c; c.i = ((unsigned int)u) << 16; return c.f;
}

// --- device-coherent (Infinity-Cache) access helpers: sc0 sc1 = bypass L1+L2.
// Stores are fire-and-forget (ordered by an explicit vmcnt drain before the
// flag store). Loads that feed MFMA use __hip_atomic_load so the COMPILER
// keeps tracking vmcnt for the consumers.
__device__ __forceinline__ void store_h16(unsigned short* p, unsigned short v) {
    asm volatile("global_store_short %0, %1, off sc0 sc1" :: "v"(p), "v"((unsigned int)v) : "memory");
}
__device__ __forceinline__ void store_flag(unsigned int* p, unsigned int v) {
    asm volatile("global_store_dword %0, %1, off sc0 sc1" :: "v"(p), "v"(v) : "memory");
}
__device__ __forceinline__ void vmem_drain() {
    asm volatile("s_waitcnt vmcnt(0)" ::: "memory");
}

// ---------------------------------------------------------------- pack inputs
// fp32 [64][1024][256] -> bf16 (rows m = b*1024+t are contiguous I=256)
__global__ void pack_inputs(const float* __restrict__ in, unsigned short* __restrict__ out) {
    int i = blockIdx.x * 256 + threadIdx.x;          // 16384 blocks: i < 4194304
    float4 v = reinterpret_cast<const float4*>(in)[i];
    ushort4 u;
    u.x = f2bf(v.x); u.y = f2bf(v.y); u.z = f2bf(v.z); u.w = f2bf(v.w);
    reinterpret_cast<ushort4*>(out)[i] = u;
}

// ---------------------------------------------------------------- pack weights
// Wx  bf16 [1536][256]  (n = g*512 + j; g: 0=r,1=z,2=n)
// Wh  bf16 [3][512][512]
// biasx fp32 [1536]: r: b_ir+b_hr, z: b_iz+b_hz, n: b_in (b_hn inside r*(...))
// Also zero-inits the 32 distributed barrier flags (ws re-poisoned every call).
__global__ void pack_weights(const float* __restrict__ w_ir, const float* __restrict__ w_iz,
                             const float* __restrict__ w_in, const float* __restrict__ b_ir,
                             const float* __restrict__ b_iz, const float* __restrict__ b_in,
                             const float* __restrict__ w_hr, const float* __restrict__ w_hz,
                             const float* __restrict__ w_hn, const float* __restrict__ b_hr,
                             const float* __restrict__ b_hz,
                             unsigned short* __restrict__ Wx, unsigned short* __restrict__ Wh,
                             float* __restrict__ biasx, unsigned int* __restrict__ flags) {
    int i = blockIdx.x * 256 + threadIdx.x;          // 3072 blocks: i < 786432
    {
        int g = i / 262144, rem = i % 262144;
        const float* src = (g == 0) ? w_hr : ((g == 1) ? w_hz : w_hn);
        Wh[i] = f2bf(src[rem]);
    }
    if (i < 393216) {
        int g = i / 131072, rem = i % 131072;
        const float* src = (g == 0) ? w_ir : ((g == 1) ? w_iz : w_in);
        Wx[i] = f2bf(src[rem]);
    }
    if (i < 1536) {
        int g = i / 512, j = i % 512;
        float v = (g == 0) ? (b_ir[j] + b_hr[j]) : ((g == 1) ? (b_iz[j] + b_hz[j]) : b_in[j]);
        biasx[i] = v;
    }
    if (i < 1024) flags[i] = 0u;    // 32 flags spaced 32 uints (128 B) apart
}

// ---------------------------------------------------------------- input projection GEMM
// C[m][n] = sum_k A[m][k]*Wx[n][k] + biasx[n],  M=65536, N=1536, K=256
// written as bf16 X[t][b][n] with t = m & 1023, b = m >> 10.
__global__ __launch_bounds__(256) void xproj_gemm(
    const unsigned short* __restrict__ A,    // [65536][256] bf16
    const unsigned short* __restrict__ Bw,   // [1536][256]  bf16
    const float* __restrict__ biasx,         // [1536]
    unsigned short* __restrict__ X)          // [1024][64][1536] bf16
{
    __shared__ __attribute__((aligned(16))) unsigned short Al[64][40]; // +8 pad
    __shared__ __attribute__((aligned(16))) unsigned short Bl[64][40];
    const int tid  = threadIdx.x;
    const int m0   = blockIdx.x * 64;
    const int n0   = blockIdx.y * 64;
    const int lane = tid & 63;
    const int wv   = tid >> 6;
    const int quad = lane >> 4;
    const int l16  = lane & 15;
    const int mw   = (wv & 1) * 32;
    const int nw   = (wv >> 1) * 32;
    const int lr   = tid >> 2;          // 0..63 staging row
    const int lc   = (tid & 3) * 8;     // k offset within BK=32

    f32x4 acc[2][2] = {};

    for (int kb = 0; kb < 8; ++kb) {
        uint4 av = *reinterpret_cast<const uint4*>(A  + (size_t)(m0 + lr) * 256 + kb * 32 + lc);
        uint4 bv = *reinterpret_cast<const uint4*>(Bw + (size_t)(n0 + lr) * 256 + kb * 32 + lc);
        __syncthreads();
        *reinterpret_cast<uint4*>(&Al[lr][lc]) = av;
        *reinterpret_cast<uint4*>(&Bl[lr][lc]) = bv;
        __syncthreads();
        bf16x8 af[2], bfg[2];
#pragma unroll
        for (int s = 0; s < 2; ++s) {
            af[s]  = *reinterpret_cast<const bf16x8*>(&Al[mw + s * 16 + l16][quad * 8]);
            bfg[s] = *reinterpret_cast<const bf16x8*>(&Bl[nw + s * 16 + l16][quad * 8]);
        }
#pragma unroll
        for (int sm = 0; sm < 2; ++sm)
#pragma unroll
            for (int sn = 0; sn < 2; ++sn)
                acc[sm][sn] = __builtin_amdgcn_mfma_f32_16x16x32_bf16(af[sm], bfg[sn], acc[sm][sn], 0, 0, 0);
    }
    // epilogue: D layout col = lane&15 (n), row = quad*4 + r (m)
#pragma unroll
    for (int sn = 0; sn < 2; ++sn) {
        int n = n0 + nw + sn * 16 + l16;
        float bias = biasx[n];
#pragma unroll
        for (int sm = 0; sm < 2; ++sm)
#pragma unroll
            for (int r = 0; r < 4; ++r) {
                int m = m0 + mw + sm * 16 + quad * 4 + r;
                int t = m & 1023, b = m >> 10;
                X[(size_t)(t * 64 + b) * 1536 + n] = f2bf(acc[sm][sn][r] + bias);
            }
    }
}

// ---------------------------------------------------------------- recurrent scan
// 32 workgroups x 256 threads, plain launch (all co-resident: 32 << 256 CUs at
// 1 block/CU). Workgroup `bid` owns output dims j in [bid*16, bid*16+16) per
// gate; weight B-fragments stay register-resident for all 1024 steps.
// h exchange: sc0/sc1 stores+loads through the Infinity Cache (device coherence
// point) -- NO cache-maintenance fences anywhere. Sync: 32 distributed
// monotone flags (one 128B-spaced line per block); release = vmcnt drain
// before the flag store; acquire = IC-coherent loads can't be stale.
__global__ __launch_bounds__(256, 1) void gru_scan(
    const unsigned short* __restrict__ X,    // [1024][64][1536] bf16 (biases folded)
    const unsigned short* __restrict__ Wh,   // [3][512][512] bf16
    const float* __restrict__ h0,            // [1][64][512]
    const float* __restrict__ b_hn,          // [512]
    unsigned short* __restrict__ Hbuf,       // [2][64][512] bf16
    unsigned int* __restrict__ flags,        // [32*32] (zeroed by pack_weights)
    float* __restrict__ out)                 // [64][1024][512] fp32, then hlast [64][512]
{
    const int tid  = threadIdx.x;
    const int lane = tid & 63;
    const int w    = tid >> 6;      // wave 0..3 -> batch rows 16w..16w+15
    const int quad = lane >> 4;
    const int jl   = lane & 15;
    const int bid  = blockIdx.x;    // 0..31
    const int jg   = bid * 16 + jl; // this lane's output dim (per gate)

    // Hoist weight B-fragments: lane n = lane&15 holds row j=jg,
    // k = kk*32 + quad*8 + (0..7) -> contiguous 16B from Wh[g][jg][...]
    bf16x8 bfrag[3][16];
#pragma unroll
    for (int g = 0; g < 3; ++g)
#pragma unroll
        for (int kk = 0; kk < 16; ++kk) {
            uint4 v = *reinterpret_cast<const uint4*>(
                Wh + (size_t)(g * 512 + jg) * 512 + kk * 32 + quad * 8);
            bfrag[g][kk] = __builtin_bit_cast(bf16x8, v);
        }
    const float bhn = b_hn[jg];

    // init h (C/D row mapping: b = 16w + quad*4 + r, col = jg); stores go to IC
    float h_reg[4];
#pragma unroll
    for (int r = 0; r < 4; ++r) {
        int b = w * 16 + quad * 4 + r;
        float h = h0[b * 512 + jg];
        h_reg[r] = h;
        store_h16(&Hbuf[b * 512 + jg], f2bf(h));
    }
    vmem_drain();
    __syncthreads();
    if (tid == 0) store_flag(&flags[bid * 32], 1u);
    if (tid < 64) {
        unsigned int* fp = &flags[(tid & 31) * 32];
        unsigned int v;
        do { v = __hip_atomic_load(fp, __ATOMIC_RELAXED, __HIP_MEMORY_SCOPE_AGENT); }
        while (!__all((int)(v >= 1u)));
    }
    __syncthreads();

    const int arow = w * 16 + jl;   // A-fragment row this lane loads (m = lane&15)

    // preload x projections for t=0
    float xv[3][4];
#pragma unroll
    for (int r = 0; r < 4; ++r) {
        int b = w * 16 + quad * 4 + r;
#pragma unroll
        for (int g = 0; g < 3; ++g)
            xv[g][r] = bf2f(X[(size_t)b * 1536 + g * 512 + jg]);
    }

    for (int t = 0; t < 1024; ++t) {
        const int cur = t & 1;
        const int nxt = cur ^ 1;

        // A fragments from IC (fresh by flag protocol): 2x u64 atomic loads per kk
        bf16x8 afrag[16];
#pragma unroll
        for (int kk = 0; kk < 16; ++kk) {
            const unsigned long long* hp = reinterpret_cast<const unsigned long long*>(
                Hbuf + (size_t)(cur * 64 + arow) * 512 + kk * 32 + quad * 8);
            unsigned long long lo = __hip_atomic_load(hp,     __ATOMIC_RELAXED, __HIP_MEMORY_SCOPE_AGENT);
            unsigned long long hi = __hip_atomic_load(hp + 1, __ATOMIC_RELAXED, __HIP_MEMORY_SCOPE_AGENT);
            ulonglong2 u; u.x = lo; u.y = hi;
            afrag[kk] = __builtin_bit_cast(bf16x8, u);
        }

        f32x4 acc[3];
#pragma unroll
        for (int g = 0; g < 3; ++g) {
            f32x4 a = {0.f, 0.f, 0.f, 0.f};
#pragma unroll
            for (int kk = 0; kk < 16; ++kk)
                a = __builtin_amdgcn_mfma_f32_16x16x32_bf16(afrag[kk], bfrag[g][kk], a, 0, 0, 0);
            acc[g] = a;
        }

#pragma unroll
        for (int r = 0; r < 4; ++r) {
            int b = w * 16 + quad * 4 + r;
            float rv = 1.f / (1.f + __expf(-(xv[0][r] + acc[0][r])));
            float zv = 1.f / (1.f + __expf(-(xv[1][r] + acc[1][r])));
            float na = xv[2][r] + rv * (acc[2][r] + bhn);
            float nv = 1.f - 2.f / (1.f + __expf(2.f * na));   // tanh, inf-safe
            float h  = (1.f - zv) * nv + zv * h_reg[r];
            h_reg[r] = h;
            out[(size_t)b * (1024 * 512) + (size_t)t * 512 + jg] = h;
            store_h16(&Hbuf[(size_t)(nxt * 64 + b) * 512 + jg], f2bf(h));
        }
        if (t == 1023) {
#pragma unroll
            for (int r = 0; r < 4; ++r) {
                int b = w * 16 + quad * 4 + r;
                out[(size_t)(64 * 1024 * 512) + b * 512 + jg] = h_reg[r];
            }
            break;   // no final barrier needed
        }

        // prefetch next step's x projections; they drain with the h stores
        {
            const unsigned short* Xt = X + (size_t)(t + 1) * (64 * 1536);
#pragma unroll
            for (int r = 0; r < 4; ++r) {
                int b = w * 16 + quad * 4 + r;
#pragma unroll
                for (int g = 0; g < 3; ++g)
                    xv[g][r] = bf2f(Xt[b * 1536 + g * 512 + jg]);
            }
        }

        // release: all my loads/stores complete (h stores acked at IC), then flag
        vmem_drain();
        __syncthreads();
        if (tid == 0) store_flag(&flags[bid * 32], (unsigned int)(t + 2));
        // wait: wave 0 polls all 32 flags (one lane each, no contention)
        if (tid < 64) {
            unsigned int tgt = (unsigned int)(t + 2);
            unsigned int* fp = &flags[(tid & 31) * 32];
            unsigned int v;
            do { v = __hip_atomic_load(fp, __ATOMIC_RELAXED, __HIP_MEMORY_SCOPE_AGENT); }
            while (!__all((int)(v >= tgt)));
        }
        __syncthreads();
    }
}

// ---------------------------------------------------------------- host
extern "C" void kernel_launch(void* const* d_in, const int* in_sizes, int n_in,
                              void* d_out, int out_size, void* d_ws, size_t ws_size,
                              hipStream_t stream) {
    const float* inputs = (const float*)d_in[0];
    const float* h0     = (const float*)d_in[1];
    const float* w_ir   = (const float*)d_in[2];
    const float* w_iz   = (const float*)d_in[3];
    const float* w_in   = (const float*)d_in[4];
    const float* b_ir   = (const float*)d_in[5];
    const float* b_iz   = (const float*)d_in[6];
    const float* b_in   = (const float*)d_in[7];
    const float* w_hr   = (const float*)d_in[8];
    const float* w_hz   = (const float*)d_in[9];
    const float* w_hn   = (const float*)d_in[10];
    const float* b_hr   = (const float*)d_in[11];
    const float* b_hz   = (const float*)d_in[12];
    const float* b_hn   = (const float*)d_in[13];
    float* out = (float*)d_out;

    // ws layout (16B aligned)
    char* wsb = (char*)d_ws;
    unsigned short* X     = (unsigned short*)(wsb);              // 201326592 B
    unsigned short* Abf   = (unsigned short*)(wsb + 201326592);  //  33554432 B
    unsigned short* Wx    = (unsigned short*)(wsb + 234881024);  //    786432 B
    unsigned short* Wh    = (unsigned short*)(wsb + 235667456);  //   1572864 B
    float*          biasx = (float*)        (wsb + 237240320);   //      6144 B
    unsigned short* Hbuf  = (unsigned short*)(wsb + 237246464);  //    131072 B
    unsigned int*   flags = (unsigned int*) (wsb + 237377536);   //      4096 B

    pack_inputs<<<16384, 256, 0, stream>>>(inputs, Abf);
    pack_weights<<<3072, 256, 0, stream>>>(w_ir, w_iz, w_in, b_ir, b_iz, b_in,
                                           w_hr, w_hz, w_hn, b_hr, b_hz, Wx, Wh, biasx, flags);
    xproj_gemm<<<dim3(1024, 24), 256, 0, stream>>>(Abf, Wx, biasx, X);
    gru_scan<<<32, 256, 0, stream>>>(X, Wh, h0, b_hn, Hbuf, flags, out);
}